// Round 3
// baseline (2294.804 us; speedup 1.0000x reference)
//
#include <hip/hip_runtime.h>
#include <hip/hip_bf16.h>

// ---------------------------------------------------------------------------
// myLSTM R3: exchange-free LSTM scan, provably register-fitting Wh partition.
//   prep_all  : x->bf16 ; Wi -> WiT [1024][256] bf16 ; Wh -> WhP permuted
//               [1024][256] bf16 with row' = w*64 + rt*16 + q*4 + r  <->
//               col_nat = gate(r)*256 + unit(w*16 + rt*4 + q)  so MFMA acc is
//               gate-aligned per lane.
//   xg_gemm   : xg = x@Wi + b (bf16 MFMA 128x128), PERMUTED [b][t][u][gate]
//               so the scan loads 4 gates as one 8B word.
//   lstm_scan : 64 WGs, one per batch; NO inter-WG traffic. 1024 thr =
//               16 waves (4/SIMD, 128-VGPR cap). Wave owns 64 Wh rows' =
//               4 tiles: 3 register-resident (96 VGPR, fits WITH margin,
//               unlike R2's 192-over-cap) + 1 in LDS (16 tiles = 128 KB,
//               XOR-swizzled). h_{t-1} (512B) double-buffered in LDS, read
//               as BROADCAST B-fragment. Per step: 8 kt x {bcast read,
//               3 reg-MFMA + 1 LDS-MFMA} -> gates in-register (act lanes
//               l16<4 own unit w*16+l16*4+quad via acc[l16]) -> h to next
//               hA buffer + hout LDS buffer -> ONE barrier. hout flushed
//               coalesced every 16 steps (no per-step global-store drain).
//               Floor: 128 MFMA/SIMD/step x 19.4cy = 2483 cy.
//   attn_head : fused attention + MLP head (block-local per batch).
// ---------------------------------------------------------------------------

typedef __attribute__((ext_vector_type(8))) short short8;   // 8 x bf16 (4 VGPR)
typedef __attribute__((ext_vector_type(4))) float float4v;  // MFMA acc

__device__ __forceinline__ unsigned short f2bf(float f) {  // RNE f32->bf16
  unsigned u = __builtin_bit_cast(unsigned, f);
  return (unsigned short)((u + 0x7fffu + ((u >> 16) & 1u)) >> 16);
}
__device__ __forceinline__ float bf2f(unsigned short h) {
  return __builtin_bit_cast(float, ((unsigned)h) << 16);
}
__device__ __forceinline__ float bcl(unsigned u) {  // low bf16 of dword
  return __builtin_bit_cast(float, u << 16);
}
__device__ __forceinline__ float bch(unsigned u) {  // high bf16 of dword
  return __builtin_bit_cast(float, u & 0xffff0000u);
}
// v_rcp_f32 (1 ulp) instead of precise div: error ~1e-7, invisible vs bf16.
__device__ __forceinline__ float sigm(float x) {
  return __builtin_amdgcn_rcpf(1.f + __expf(-x));
}
__device__ __forceinline__ float tanh_f(float x) {
  return 1.f - 2.f * __builtin_amdgcn_rcpf(1.f + __expf(2.f * x));
}

// ---------------------------------------------------------------- prep (fused)
// blocks [0,8192)    : x fp32 -> bf16                (8,388,608 elems)
// blocks [8192,8448) : Wi [256,1024] -> WiT [1024][256] bf16
// blocks [8448,8704) : Wh [256,1024] -> WhP [1024][256] bf16, row-permuted
__global__ void prep_all(const float* __restrict__ x,
                         const float* __restrict__ Wi,
                         const float* __restrict__ Wh,
                         unsigned short* __restrict__ xbf,
                         unsigned short* __restrict__ WiT,
                         unsigned short* __restrict__ WhP) {
  const int bid = blockIdx.x, tid = threadIdx.x;
  if (bid < 8192) {
    size_t i = ((size_t)bid * 256 + tid) * 4;
    float4 v = *(const float4*)&x[i];
    unsigned long long pk = (unsigned long long)f2bf(v.x)
                          | ((unsigned long long)f2bf(v.y) << 16)
                          | ((unsigned long long)f2bf(v.z) << 32)
                          | ((unsigned long long)f2bf(v.w) << 48);
    *(unsigned long long*)&xbf[i] = pk;
  } else if (bid < 8448) {
    size_t i = ((size_t)(bid - 8192) * 256 + tid) * 4;
    float4 v = *(const float4*)&Wi[i];
    int k = (int)(i >> 10), n = (int)(i & 1023);
    WiT[(size_t)(n + 0) * 256 + k] = f2bf(v.x);
    WiT[(size_t)(n + 1) * 256 + k] = f2bf(v.y);
    WiT[(size_t)(n + 2) * 256 + k] = f2bf(v.z);
    WiT[(size_t)(n + 3) * 256 + k] = f2bf(v.w);
  } else {
    size_t i0 = ((size_t)(bid - 8448) * 256 + tid) * 4;
    int row = (int)(i0 >> 8);  // row' (same for all 4 elems)
    // row' = w*64 + rt*16 + q*4 + r  ->  col_nat = r*256 + w*16 + rt*4 + q
    int colnat = (row & 3) * 256 + (row >> 6) * 16 + ((row >> 4) & 3) * 4 +
                 ((row >> 2) & 3);
    unsigned long long pk = 0;
#pragma unroll
    for (int j = 0; j < 4; ++j) {
      int k = (int)((i0 + j) & 255);
      pk |= (unsigned long long)f2bf(Wh[(size_t)k * 1024 + colnat]) << (16 * j);
    }
    *(unsigned long long*)&WhP[i0] = pk;
  }
}

// ---------------------------------------------------------------- xg = x@Wi+b
#define XKP 40  // LDS k-pitch (shorts): 80B rows -> 16B-aligned b128, ~2-way banks
__global__ __launch_bounds__(256) void xg_gemm(const unsigned short* __restrict__ xbf,
                                               const unsigned short* __restrict__ WiT,
                                               const float* __restrict__ bias,
                                               unsigned short* __restrict__ xg) {
  __shared__ unsigned short As[128 * XKP];
  __shared__ unsigned short Bs[128 * XKP];
  const int tid = threadIdx.x;
  const int n0 = blockIdx.x * 128, m0 = blockIdx.y * 128;
  const int wave = tid >> 6, lane = tid & 63, quad = lane >> 4, l16 = lane & 15;
  const int wm = wave >> 1, wn = wave & 1;

  float4v acc[4][4];
#pragma unroll
  for (int i = 0; i < 4; ++i)
#pragma unroll
    for (int j = 0; j < 4; ++j) acc[i][j] = (float4v){0.f, 0.f, 0.f, 0.f};

  const int rr = tid >> 2, c8 = (tid & 3) * 8;  // staging coords (16B per thread)
  for (int k0 = 0; k0 < 256; k0 += 32) {
#pragma unroll
    for (int pp = 0; pp < 2; ++pp) {
      int r = pp * 64 + rr;
      *(uint4*)&As[r * XKP + c8] = *(const uint4*)&xbf[(size_t)(m0 + r) * 256 + k0 + c8];
      *(uint4*)&Bs[r * XKP + c8] = *(const uint4*)&WiT[(size_t)(n0 + r) * 256 + k0 + c8];
    }
    __syncthreads();
#pragma unroll
    for (int mt = 0; mt < 4; ++mt) {
      short8 af = *(const short8*)&As[(wm * 64 + mt * 16 + l16) * XKP + quad * 8];
#pragma unroll
      for (int nt = 0; nt < 4; ++nt) {
        short8 bf = *(const short8*)&Bs[(wn * 64 + nt * 16 + l16) * XKP + quad * 8];
        acc[mt][nt] = __builtin_amdgcn_mfma_f32_16x16x32_bf16(af, bf, acc[mt][nt], 0, 0, 0);
      }
    }
    __syncthreads();
  }
  // epilogue: +bias, bf16 store, PERMUTED layout for the scan:
  //   xg[((b*512 + t)*256 + u)*4 + gate]   (4 gates of a unit contiguous, 8B)
#pragma unroll
  for (int nt = 0; nt < 4; ++nt) {
    int col = n0 + wn * 64 + nt * 16 + l16;
    int gate = col >> 8, u = col & 255;
    float bv = bias[col];
#pragma unroll
    for (int mt = 0; mt < 4; ++mt) {
#pragma unroll
      for (int r = 0; r < 4; ++r) {
        int row = m0 + wm * 64 + mt * 16 + quad * 4 + r;
        int b = row >> 9, t = row & 511;
        xg[(((size_t)b * 512 + t) * 256 + u) * 4 + gate] = f2bf(acc[mt][nt][r] + bv);
      }
    }
  }
}

// ---------------------------------------------------------------- LSTM scan
// 64 WGs, one batch each. 1024 threads = 16 waves (4/SIMD, <=128 VGPR/wave).
// Wave w owns Wh rows' [w*64, w*64+64): tiles rt=0..2 in registers (96 VGPR),
// tile rt=3 in LDS (swizzled). h_{t-1} (512B) double-buffered, broadcast-read.
__global__ __launch_bounds__(1024) void lstm_scan(
    const unsigned short* __restrict__ WhP,  // [1024][256] bf16 (permuted rows)
    const unsigned short* __restrict__ xg,   // [b][t][u][gate] bf16
    unsigned short* __restrict__ hout) {
  __shared__ unsigned short WhL[16 * 4096];     // 16 tiles x 8KB = 131072 B
  __shared__ unsigned short hA[2][256];         // 1 KB, double-buffered h
  __shared__ unsigned short hoB[2][16][256];    // 16 KB, hout staging
  const int tid = threadIdx.x;
  const int b = blockIdx.x;  // batch
  const int wave = tid >> 6, lane = tid & 63, quad = lane >> 4, l16 = lane & 15;

  // ---- preload 3 register tiles: frA[rt][kt] = WhP[w*64+rt*16+l16][kt*32+quad*8..]
  short8 frA[3][8];
  {
    const unsigned short* src = WhP + ((size_t)wave * 64 + l16) * 256 + quad * 8;
#pragma unroll
    for (int rt = 0; rt < 3; ++rt)
#pragma unroll
      for (int kt = 0; kt < 8; ++kt)
        frA[rt][kt] = *(const short8*)&src[rt * 4096 + kt * 32];
  }
  // ---- stage LDS tile rt=3 (rows w*64+48 .. +16), XOR-swizzled
#pragma unroll
  for (int i = 0; i < 8; ++i) {
    int idx = i * 64 + lane;             // 512 16B-chunks per tile
    int rw = idx >> 5, ch = idx & 31;    // row 0..15, chunk 0..31
    uint4 v = *(const uint4*)&WhP[((size_t)wave * 64 + 48 + rw) * 256 + ch * 8];
    *(uint4*)((char*)WhL + wave * 8192 + rw * 512 + ((ch * 16) ^ ((rw & 7) << 4))) = v;
  }
  if (tid < 512) ((unsigned short*)hA)[tid] = 0;  // h_{-1} = 0 (both buffers)

  const bool act = (l16 < 4);                  // gate-owning lanes (16/wave)
  const int u = wave * 16 + l16 * 4 + quad;    // this lane's unit (if act)
  const unsigned short* xgp = xg + ((size_t)b * 512 * 256 + u) * 4;
  unsigned short* houtb = hout + (size_t)b * 512 * 256;
  const char* tileA = (const char*)WhL + wave * 8192 + l16 * 512;
  float c = 0.f;

  __syncthreads();

  for (int t = 0; t < 512; ++t) {
    // xg(t): 4 gates of this lane's unit, one 8B load; consumed ~2000cy later
    unsigned long long xv = 0;
    if (act) xv = *(const unsigned long long*)(xgp + (size_t)t * 1024);

    // ---- coalesced hout flush of the PREVIOUS 16-step half (off critical path)
    if ((t & 15) == 0 && t) {
      int hf = ((t >> 4) & 1) ^ 1;
      int row = tid >> 6, u0 = (lane) * 4;
      unsigned long long hv = *(const unsigned long long*)&hoB[hf][row][u0];
      *(unsigned long long*)&houtb[(size_t)(t - 16 + row) * 256 + u0] = hv;
    }

    // ---- MFMA sweep: 8 kt x (3 register tiles + 1 LDS tile)
    const unsigned short* hbuf = hA[t & 1];
    float4v acc[4];
#pragma unroll
    for (int rt = 0; rt < 4; ++rt) acc[rt] = (float4v){0.f, 0.f, 0.f, 0.f};
#pragma unroll
    for (int kt = 0; kt < 8; ++kt) {
      // broadcast h chunk: same 16B for all l16 of a quad -> conflict-free
      short8 hb = *(const short8*)((const char*)hbuf + kt * 64 + quad * 16);
      acc[0] = __builtin_amdgcn_mfma_f32_16x16x32_bf16(frA[0][kt], hb, acc[0], 0, 0, 0);
      acc[1] = __builtin_amdgcn_mfma_f32_16x16x32_bf16(frA[1][kt], hb, acc[1], 0, 0, 0);
      acc[2] = __builtin_amdgcn_mfma_f32_16x16x32_bf16(frA[2][kt], hb, acc[2], 0, 0, 0);
      short8 a3 = *(const short8*)(tileA + ((kt * 64 + quad * 16) ^ ((l16 & 7) << 4)));
      acc[3] = __builtin_amdgcn_mfma_f32_16x16x32_bf16(a3, hb, acc[3], 0, 0, 0);
    }

    if (act) {
      // lane's tile: rt == l16 (3 cndmask selects)
      float4v g4 = acc[0];
      if (l16 == 1) g4 = acc[1];
      if (l16 == 2) g4 = acc[2];
      if (l16 == 3) g4 = acc[3];
      // g4[r]: gate r (i,f,g,o) of unit u
      float gi = g4[0] + bf2f((unsigned short)(xv));
      float gf = g4[1] + bf2f((unsigned short)(xv >> 16));
      float gG = g4[2] + bf2f((unsigned short)(xv >> 32));
      float go = g4[3] + bf2f((unsigned short)(xv >> 48));
      float cc = sigm(gf) * c + sigm(gi) * tanh_f(gG);
      c = cc;
      unsigned short h16 = f2bf(sigm(go) * tanh_f(cc));
      hA[(t + 1) & 1][u] = h16;        // next h buffer (disjoint from readers)
      hoB[(t >> 4) & 1][t & 15][u] = h16;
    }
    __syncthreads();  // h_t + hoB slot visible for next step
  }
  // ---- final flush: steps 496..511 (half 1)
  {
    int row = tid >> 6, u0 = (lane) * 4;
    unsigned long long hv = *(const unsigned long long*)&hoB[1][row][u0];
    *(unsigned long long*)&houtb[(size_t)(496 + row) * 256 + u0] = hv;
  }
}

// --------------------------------------------------- attention + head (fused)
__global__ __launch_bounds__(256) void attn_head(
    const unsigned short* __restrict__ hout,
    const float* __restrict__ Wq, const float* __restrict__ bq,
    const float* __restrict__ Wk, const float* __restrict__ bk,
    const float* __restrict__ Wv, const float* __restrict__ bv,
    const float* __restrict__ Wo, const float* __restrict__ bo,
    const float* __restrict__ W1, const float* __restrict__ b1,
    const float* __restrict__ W2, const float* __restrict__ b2,
    float* __restrict__ out) {
  __shared__ float h0S[256], q0S[256], red[256], usS[256], sS[512], hb4[4][256];
  __shared__ float oS[256], o1S[256], zS[32], cbS;
  const int b = blockIdx.x, tid = threadIdx.x, wave = tid >> 6, lane = tid & 63;
  const size_t hb_base = (size_t)b * 512 * 256;

  // ---- q0 = h0@Wq+bq ; u = Wk@(scale*q0) ; cb = scale*q0.bk
  h0S[tid] = bf2f(hout[hb_base + tid]);
  __syncthreads();
  float a = 0.f;
  for (int k = 0; k < 256; ++k) a += h0S[k] * Wq[(size_t)k * 256 + tid];
  q0S[tid] = a + bq[tid];
  __syncthreads();
  red[tid] = q0S[tid] * bk[tid];
  __syncthreads();
  for (int s = 128; s > 0; s >>= 1) {
    if (tid < s) red[tid] += red[tid + s];
    __syncthreads();
  }
  if (tid == 0) cbS = 0.0625f * red[0];
  float acq = 0.f;
  const float* wr = &Wk[(size_t)tid * 256];
  for (int e = 0; e < 256; e += 4) {
    float4 w = *(const float4*)&wr[e];
    acq += w.x * q0S[e] + w.y * q0S[e + 1] + w.z * q0S[e + 2] + w.w * q0S[e + 3];
  }
  usS[tid] = 0.0625f * acq;
  __syncthreads();

  // ---- scores = u.h[b,t]+cb -> softmax -> hbar = sum attn*h
  const float u0 = usS[lane * 4 + 0], u1 = usS[lane * 4 + 1];
  const float u2 = usS[lane * 4 + 2], u3 = usS[lane * 4 + 3];
  const float cbv = cbS;
  for (int i = 0; i < 128; ++i) {
    int t = i * 4 + wave;
    unsigned long long hv = *(const unsigned long long*)&hout[hb_base + (size_t)t * 256 + lane * 4];
    unsigned lo = (unsigned)hv, hi = (unsigned)(hv >> 32);
    float p = u0 * bcl(lo) + u1 * bch(lo) + u2 * bcl(hi) + u3 * bch(hi);
    for (int m = 1; m < 64; m <<= 1) p += __shfl_xor(p, m, 64);
    if (lane == 0) sS[t] = p + cbv;
  }
  __syncthreads();
  red[tid] = fmaxf(sS[tid], sS[tid + 256]);
  __syncthreads();
  for (int s = 128; s > 0; s >>= 1) {
    if (tid < s) red[tid] = fmaxf(red[tid], red[tid + s]);
    __syncthreads();
  }
  float mx = red[0];
  __syncthreads();
  float e0 = __expf(sS[tid] - mx), e1 = __expf(sS[tid + 256] - mx);
  sS[tid] = e0; sS[tid + 256] = e1;
  red[tid] = e0 + e1;
  __syncthreads();
  for (int s = 128; s > 0; s >>= 1) {
    if (tid < s) red[tid] += red[tid + s];
    __syncthreads();
  }
  float inv = 1.f / red[0];
  float a0 = 0.f, a1 = 0.f, a2 = 0.f, a3 = 0.f;
  const int d0 = lane * 4;
  for (int i = 0; i < 128; ++i) {
    int t = wave * 128 + i;
    float w = sS[t];
    unsigned long long hv = *(const unsigned long long*)&hout[hb_base + (size_t)t * 256 + d0];
    unsigned lo = (unsigned)hv, hi = (unsigned)(hv >> 32);
    a0 += w * bcl(lo); a1 += w * bch(lo); a2 += w * bcl(hi); a3 += w * bch(hi);
  }
  hb4[wave][d0] = a0; hb4[wave][d0 + 1] = a1; hb4[wave][d0 + 2] = a2; hb4[wave][d0 + 3] = a3;
  __syncthreads();
  h0S[tid] = (hb4[0][tid] + hb4[1][tid] + hb4[2][tid] + hb4[3][tid]) * inv;  // hbar
  __syncthreads();

  // ---- head: o0=hbar@Wv+bv ; o1=o0@Wo+bo ; z=relu(o1@W1+b1) ; out=z@W2+b2
  a = 0.f;
  for (int k = 0; k < 256; ++k) a += h0S[k] * Wv[(size_t)k * 256 + tid];
  oS[tid] = a + bv[tid];
  __syncthreads();
  a = 0.f;
  for (int k = 0; k < 256; ++k) a += oS[k] * Wo[(size_t)k * 256 + tid];
  o1S[tid] = a + bo[tid];
  __syncthreads();
  if (tid < 32) {
    a = 0.f;
    for (int k = 0; k < 256; ++k) a += o1S[k] * W1[k * 32 + tid];
    zS[tid] = fmaxf(a + b1[tid], 0.f);
  }
  __syncthreads();
  if (tid < 3) {
    a = 0.f;
    for (int j = 0; j < 32; ++j) a += zS[j] * W2[j * 3 + tid];
    out[b * 3 + tid] = a + b2[tid];
  }
}

// ---------------------------------------------------------------- launch
extern "C" void kernel_launch(void* const* d_in, const int* in_sizes, int n_in,
                              void* d_out, int out_size, void* d_ws, size_t ws_size,
                              hipStream_t stream) {
  const float* x  = (const float*)d_in[0];
  const float* Wi = (const float*)d_in[1];
  const float* Wh = (const float*)d_in[2];
  const float* bG = (const float*)d_in[3];
  const float* Wq = (const float*)d_in[4];
  const float* bq = (const float*)d_in[5];
  const float* Wk = (const float*)d_in[6];
  const float* bk = (const float*)d_in[7];
  const float* Wv = (const float*)d_in[8];
  const float* bv = (const float*)d_in[9];
  const float* Wo = (const float*)d_in[10];
  const float* bo = (const float*)d_in[11];
  const float* W1 = (const float*)d_in[12];
  const float* b1 = (const float*)d_in[13];
  const float* W2 = (const float*)d_in[14];
  const float* b2 = (const float*)d_in[15];
  float* out = (float*)d_out;
  char* ws = (char*)d_ws;

  unsigned short* xg   = (unsigned short*)(ws);              // 67,108,864 B
  unsigned short* hout = (unsigned short*)(ws + 67108864);   // 16,777,216 B
  unsigned short* xbf  = (unsigned short*)(ws + 83886080);   // 16,777,216 B
  unsigned short* WiT  = (unsigned short*)(ws + 100663296);  //    524,288 B
  unsigned short* WhP  = (unsigned short*)(ws + 101187584);  //    524,288 B
  // total ~101.7 MB of workspace

  prep_all<<<dim3(8704), dim3(256), 0, stream>>>(x, Wi, Wh, xbf, WiT, WhP);
  xg_gemm<<<dim3(8, 256), dim3(256), 0, stream>>>(xbf, WiT, bG, xg);
  lstm_scan<<<dim3(64), dim3(1024), 0, stream>>>(WhP, xg, hout);
  attn_head<<<dim3(64), dim3(256), 0, stream>>>(hout, Wq, bq, Wk, bk, Wv, bv,
                                                Wo, bo, W1, b1, W2, b2, out);
}

// Round 4
// 1474.747 us; speedup vs baseline: 1.5561x; 1.5561x over previous
//
#include <hip/hip_runtime.h>
#include <hip/hip_bf16.h>

// ---------------------------------------------------------------------------
// myLSTM R4: exchange-free LSTM scan with a register partition that has SLACK.
//
// Register-file arithmetic (the R2/R3 failure): per-SIMD pool = 512 regs.
// Wh register-resident share (48 of 64 tiles) = 1536 regs = 75% of the CU
// file. At 8 or 16 waves the per-wave need lands at 95-105% of the cap ->
// allocator spills the loop-invariant Wh fragments -> L2 re-fetch every step.
// Only W=4 (256 thr, 1 wave/SIMD, cap 512 via __launch_bounds__(256,1)) gives
// slack: frA 12 tiles = 384 + hb8 32 + acc 16 + al 32 + misc ~16 = ~480 < 512.
//
//   prep_all  : x->bf16 ; Wi -> WiT [1024][256] bf16 ; Wh -> WhP permuted
//               [1024][256] bf16, row' = w*256 + rt*16 + q*4 + r  <->
//               col_nat = gate(r)*256 + unit(w*64 + rt*4 + q).
//   xg_gemm   : xg = x@Wi + b (bf16 MFMA 128x128), PERMUTED [b][t][u][gate].
//   lstm_scan : 64 WGs (one batch each), 256 thr = 4 waves, 1/SIMD.
//               Wave owns 256 Wh rows' = 16 tiles: 12 register-resident,
//               4 in LDS (16 tiles = 128 KB, XOR-swizzled: 8x16B slots/row
//               -> perfectly bank-balanced b128 reads). h_{t-1} (512B)
//               double-buffered in LDS, broadcast B-fragment (hb8 in regs).
//               Latency (1 wave/SIMD) is hand-pipelined: hb8 batch at step
//               top, al[8] batch per group, acc x4 MFMA chains, xg issued a
//               step ahead. All 256 lanes own exactly one unit
//               (u = w*64 + l16*4 + quad, act tile rtid == l16).
//               One barrier/step. Step ~1600-2500 cy.
//   attn_head : fused attention + MLP head (block-local per batch).
// ---------------------------------------------------------------------------

typedef __attribute__((ext_vector_type(8))) short short8;   // 8 x bf16 (4 VGPR)
typedef __attribute__((ext_vector_type(4))) float float4v;  // MFMA acc

__device__ __forceinline__ unsigned short f2bf(float f) {  // RNE f32->bf16
  unsigned u = __builtin_bit_cast(unsigned, f);
  return (unsigned short)((u + 0x7fffu + ((u >> 16) & 1u)) >> 16);
}
__device__ __forceinline__ float bf2f(unsigned short h) {
  return __builtin_bit_cast(float, ((unsigned)h) << 16);
}
__device__ __forceinline__ float bcl(unsigned u) {  // low bf16 of dword
  return __builtin_bit_cast(float, u << 16);
}
__device__ __forceinline__ float bch(unsigned u) {  // high bf16 of dword
  return __builtin_bit_cast(float, u & 0xffff0000u);
}
// v_rcp_f32 (1 ulp) instead of precise div: error ~1e-7, invisible vs bf16.
__device__ __forceinline__ float sigm(float x) {
  return __builtin_amdgcn_rcpf(1.f + __expf(-x));
}
__device__ __forceinline__ float tanh_f(float x) {
  return 1.f - 2.f * __builtin_amdgcn_rcpf(1.f + __expf(2.f * x));
}

// ---------------------------------------------------------------- prep (fused)
// blocks [0,8192)    : x fp32 -> bf16                (8,388,608 elems)
// blocks [8192,8448) : Wi [256,1024] -> WiT [1024][256] bf16
// blocks [8448,8704) : Wh [256,1024] -> WhP [1024][256] bf16, row-permuted
__global__ void prep_all(const float* __restrict__ x,
                         const float* __restrict__ Wi,
                         const float* __restrict__ Wh,
                         unsigned short* __restrict__ xbf,
                         unsigned short* __restrict__ WiT,
                         unsigned short* __restrict__ WhP) {
  const int bid = blockIdx.x, tid = threadIdx.x;
  if (bid < 8192) {
    size_t i = ((size_t)bid * 256 + tid) * 4;
    float4 v = *(const float4*)&x[i];
    unsigned long long pk = (unsigned long long)f2bf(v.x)
                          | ((unsigned long long)f2bf(v.y) << 16)
                          | ((unsigned long long)f2bf(v.z) << 32)
                          | ((unsigned long long)f2bf(v.w) << 48);
    *(unsigned long long*)&xbf[i] = pk;
  } else if (bid < 8448) {
    size_t i = ((size_t)(bid - 8192) * 256 + tid) * 4;
    float4 v = *(const float4*)&Wi[i];
    int k = (int)(i >> 10), n = (int)(i & 1023);
    WiT[(size_t)(n + 0) * 256 + k] = f2bf(v.x);
    WiT[(size_t)(n + 1) * 256 + k] = f2bf(v.y);
    WiT[(size_t)(n + 2) * 256 + k] = f2bf(v.z);
    WiT[(size_t)(n + 3) * 256 + k] = f2bf(v.w);
  } else {
    size_t i0 = ((size_t)(bid - 8448) * 256 + tid) * 4;
    int row = (int)(i0 >> 8);  // row' (same for all 4 elems)
    // row' = w*256 + rt*16 + q*4 + r -> col_nat = r*256 + w*64 + rt*4 + q
    int colnat = (row & 3) * 256 + (row >> 8) * 64 + ((row >> 4) & 15) * 4 +
                 ((row >> 2) & 3);
    unsigned long long pk = 0;
#pragma unroll
    for (int j = 0; j < 4; ++j) {
      int k = (int)((i0 + j) & 255);
      pk |= (unsigned long long)f2bf(Wh[(size_t)k * 1024 + colnat]) << (16 * j);
    }
    *(unsigned long long*)&WhP[i0] = pk;
  }
}

// ---------------------------------------------------------------- xg = x@Wi+b
#define XKP 40  // LDS k-pitch (shorts): 80B rows -> 16B-aligned b128, ~2-way banks
__global__ __launch_bounds__(256) void xg_gemm(const unsigned short* __restrict__ xbf,
                                               const unsigned short* __restrict__ WiT,
                                               const float* __restrict__ bias,
                                               unsigned short* __restrict__ xg) {
  __shared__ unsigned short As[128 * XKP];
  __shared__ unsigned short Bs[128 * XKP];
  const int tid = threadIdx.x;
  const int n0 = blockIdx.x * 128, m0 = blockIdx.y * 128;
  const int wave = tid >> 6, lane = tid & 63, quad = lane >> 4, l16 = lane & 15;
  const int wm = wave >> 1, wn = wave & 1;

  float4v acc[4][4];
#pragma unroll
  for (int i = 0; i < 4; ++i)
#pragma unroll
    for (int j = 0; j < 4; ++j) acc[i][j] = (float4v){0.f, 0.f, 0.f, 0.f};

  const int rr = tid >> 2, c8 = (tid & 3) * 8;  // staging coords (16B per thread)
  for (int k0 = 0; k0 < 256; k0 += 32) {
#pragma unroll
    for (int pp = 0; pp < 2; ++pp) {
      int r = pp * 64 + rr;
      *(uint4*)&As[r * XKP + c8] = *(const uint4*)&xbf[(size_t)(m0 + r) * 256 + k0 + c8];
      *(uint4*)&Bs[r * XKP + c8] = *(const uint4*)&WiT[(size_t)(n0 + r) * 256 + k0 + c8];
    }
    __syncthreads();
#pragma unroll
    for (int mt = 0; mt < 4; ++mt) {
      short8 af = *(const short8*)&As[(wm * 64 + mt * 16 + l16) * XKP + quad * 8];
#pragma unroll
      for (int nt = 0; nt < 4; ++nt) {
        short8 bf = *(const short8*)&Bs[(wn * 64 + nt * 16 + l16) * XKP + quad * 8];
        acc[mt][nt] = __builtin_amdgcn_mfma_f32_16x16x32_bf16(af, bf, acc[mt][nt], 0, 0, 0);
      }
    }
    __syncthreads();
  }
  // epilogue: +bias, bf16 store, PERMUTED layout for the scan:
  //   xg[((b*512 + t)*256 + u)*4 + gate]   (4 gates of a unit contiguous, 8B)
#pragma unroll
  for (int nt = 0; nt < 4; ++nt) {
    int col = n0 + wn * 64 + nt * 16 + l16;
    int gate = col >> 8, u = col & 255;
    float bv = bias[col];
#pragma unroll
    for (int mt = 0; mt < 4; ++mt) {
#pragma unroll
      for (int r = 0; r < 4; ++r) {
        int row = m0 + wm * 64 + mt * 16 + quad * 4 + r;
        int b = row >> 9, t = row & 511;
        xg[(((size_t)b * 512 + t) * 256 + u) * 4 + gate] = f2bf(acc[mt][nt][r] + bv);
      }
    }
  }
}

// ---------------------------------------------------------------- LSTM scan
// 64 WGs, one batch each. 256 threads = 4 waves, 1 wave/SIMD, 512-reg budget.
// Wave w owns Wh rows' [w*256, w*256+256) = 16 tiles: in each group gq,
// rtid = gq*4 + {0,1,2} register-resident, rtid = gq*4+3 in LDS.
// Lane (quad,l16) owns unit u = w*64 + l16*4 + quad, act tile rtid == l16.
__global__ __launch_bounds__(256, 1) void lstm_scan(
    const unsigned short* __restrict__ WhP,  // [1024][256] bf16 (permuted rows)
    const unsigned short* __restrict__ xg,   // [b][t][u][gate] bf16
    unsigned short* __restrict__ hout) {
  __shared__ unsigned short WhL[16 * 4096];     // 16 tiles x 8KB = 131072 B
  __shared__ unsigned short hA[2][256];         // 1 KB, double-buffered h
  const int tid = threadIdx.x;
  const int b = blockIdx.x;  // batch
  const int wave = tid >> 6, lane = tid & 63, quad = lane >> 4, l16 = lane & 15;

  // ---- 12 register tiles: ft = gq*3+j (j=0..2) <-> rtid = gq*4+j
  short8 frA[12][8];
#pragma unroll
  for (int gq = 0; gq < 4; ++gq)
#pragma unroll
    for (int j = 0; j < 3; ++j) {
      const int rtid = gq * 4 + j;
      const unsigned short* src =
          WhP + ((size_t)wave * 256 + rtid * 16 + l16) * 256 + quad * 8;
#pragma unroll
      for (int kt = 0; kt < 8; ++kt)
        frA[gq * 3 + j][kt] = *(const short8*)&src[kt * 32];
    }
  // ---- 4 LDS tiles per wave (rtid = gq*4+3), XOR-swizzled
#pragma unroll
  for (int i = 0; i < 32; ++i) {
    int gq = i >> 3;
    int chunk = (i & 7) * 64 + lane;     // 0..511 16B-chunks within the tile
    int rw = chunk >> 5, ch = chunk & 31;
    uint4 v = *(const uint4*)&WhP[((size_t)wave * 256 + (gq * 4 + 3) * 16 + rw) * 256 + ch * 8];
    *(uint4*)((char*)WhL + (wave * 4 + gq) * 8192 + rw * 512 +
              ((ch * 16) ^ ((rw & 7) << 4))) = v;
  }
  ((unsigned short*)hA)[tid] = 0;        // h_{-1} = 0 (both buffers)
  ((unsigned short*)hA)[tid + 256] = 0;
  __syncthreads();

  const int u = wave * 64 + l16 * 4 + quad;    // this lane's unit
  const unsigned short* xgp = xg + ((size_t)b * 512 * 256 + u) * 4;
  unsigned short* houtp = hout + (size_t)b * 512 * 256 + u;
  const char* ldsT = (const char*)WhL + wave * 4 * 8192 + l16 * 512;
  float c = 0.f;

  for (int t = 0; t < 512; ++t) {
    // xg(t): 4 gates of this lane's unit, 8B; consumed ~1500cy later
    unsigned long long xv = *(const unsigned long long*)(xgp + (size_t)t * 1024);

    // h_{t-1} broadcast fragments, batched (8 independent ds reads)
    const char* hbuf = (const char*)hA[t & 1];
    short8 hb8[8];
#pragma unroll
    for (int kt = 0; kt < 8; ++kt)
      hb8[kt] = *(const short8*)(hbuf + kt * 64 + quad * 16);

    float4v g4 = (float4v){0.f, 0.f, 0.f, 0.f};
#pragma unroll
    for (int gq = 0; gq < 4; ++gq) {
      // batch the LDS-tile reads for this group (independent, pipelined)
      short8 al[8];
#pragma unroll
      for (int kt = 0; kt < 8; ++kt)
        al[kt] = *(const short8*)(ldsT + gq * 8192 +
                                  ((kt * 64 + quad * 16) ^ ((l16 & 7) << 4)));
      float4v a0 = (float4v){0.f, 0.f, 0.f, 0.f};
      float4v a1 = a0, a2 = a0, a3 = a0;
#pragma unroll
      for (int kt = 0; kt < 8; ++kt) {  // 4 independent MFMA chains
        a0 = __builtin_amdgcn_mfma_f32_16x16x32_bf16(frA[gq * 3 + 0][kt], hb8[kt], a0, 0, 0, 0);
        a1 = __builtin_amdgcn_mfma_f32_16x16x32_bf16(frA[gq * 3 + 1][kt], hb8[kt], a1, 0, 0, 0);
        a2 = __builtin_amdgcn_mfma_f32_16x16x32_bf16(frA[gq * 3 + 2][kt], hb8[kt], a2, 0, 0, 0);
        a3 = __builtin_amdgcn_mfma_f32_16x16x32_bf16(al[kt], hb8[kt], a3, 0, 0, 0);
      }
      // extraction: lane's act tile is rtid == l16
      if (l16 == gq * 4 + 0) g4 = a0;
      if (l16 == gq * 4 + 1) g4 = a1;
      if (l16 == gq * 4 + 2) g4 = a2;
      if (l16 == gq * 4 + 3) g4 = a3;
    }

    // gates (every lane owns one unit)
    float gi = g4[0] + bf2f((unsigned short)(xv));
    float gf = g4[1] + bf2f((unsigned short)(xv >> 16));
    float gG = g4[2] + bf2f((unsigned short)(xv >> 32));
    float go = g4[3] + bf2f((unsigned short)(xv >> 48));
    float cc = sigm(gf) * c + sigm(gi) * tanh_f(gG);
    c = cc;
    unsigned short h16 = f2bf(sigm(go) * tanh_f(cc));
    hA[(t + 1) & 1][u] = h16;            // next buffer (disjoint from readers)
    houtp[(size_t)t * 256] = h16;        // h history for attention
    __syncthreads();                     // ONE barrier per step
  }
}

// --------------------------------------------------- attention + head (fused)
__global__ __launch_bounds__(256) void attn_head(
    const unsigned short* __restrict__ hout,
    const float* __restrict__ Wq, const float* __restrict__ bq,
    const float* __restrict__ Wk, const float* __restrict__ bk,
    const float* __restrict__ Wv, const float* __restrict__ bv,
    const float* __restrict__ Wo, const float* __restrict__ bo,
    const float* __restrict__ W1, const float* __restrict__ b1,
    const float* __restrict__ W2, const float* __restrict__ b2,
    float* __restrict__ out) {
  __shared__ float h0S[256], q0S[256], red[256], usS[256], sS[512], hb4[4][256];
  __shared__ float oS[256], o1S[256], zS[32], cbS;
  const int b = blockIdx.x, tid = threadIdx.x, wave = tid >> 6, lane = tid & 63;
  const size_t hb_base = (size_t)b * 512 * 256;

  // ---- q0 = h0@Wq+bq ; u = Wk@(scale*q0) ; cb = scale*q0.bk
  h0S[tid] = bf2f(hout[hb_base + tid]);
  __syncthreads();
  float a = 0.f;
  for (int k = 0; k < 256; ++k) a += h0S[k] * Wq[(size_t)k * 256 + tid];
  q0S[tid] = a + bq[tid];
  __syncthreads();
  red[tid] = q0S[tid] * bk[tid];
  __syncthreads();
  for (int s = 128; s > 0; s >>= 1) {
    if (tid < s) red[tid] += red[tid + s];
    __syncthreads();
  }
  if (tid == 0) cbS = 0.0625f * red[0];
  float acq = 0.f;
  const float* wr = &Wk[(size_t)tid * 256];
  for (int e = 0; e < 256; e += 4) {
    float4 w = *(const float4*)&wr[e];
    acq += w.x * q0S[e] + w.y * q0S[e + 1] + w.z * q0S[e + 2] + w.w * q0S[e + 3];
  }
  usS[tid] = 0.0625f * acq;
  __syncthreads();

  // ---- scores = u.h[b,t]+cb -> softmax -> hbar = sum attn*h
  const float u0 = usS[lane * 4 + 0], u1 = usS[lane * 4 + 1];
  const float u2 = usS[lane * 4 + 2], u3 = usS[lane * 4 + 3];
  const float cbv = cbS;
  for (int i = 0; i < 128; ++i) {
    int t = i * 4 + wave;
    unsigned long long hv = *(const unsigned long long*)&hout[hb_base + (size_t)t * 256 + lane * 4];
    unsigned lo = (unsigned)hv, hi = (unsigned)(hv >> 32);
    float p = u0 * bcl(lo) + u1 * bch(lo) + u2 * bcl(hi) + u3 * bch(hi);
    for (int m = 1; m < 64; m <<= 1) p += __shfl_xor(p, m, 64);
    if (lane == 0) sS[t] = p + cbv;
  }
  __syncthreads();
  red[tid] = fmaxf(sS[tid], sS[tid + 256]);
  __syncthreads();
  for (int s = 128; s > 0; s >>= 1) {
    if (tid < s) red[tid] = fmaxf(red[tid], red[tid + s]);
    __syncthreads();
  }
  float mx = red[0];
  __syncthreads();
  float e0 = __expf(sS[tid] - mx), e1 = __expf(sS[tid + 256] - mx);
  sS[tid] = e0; sS[tid + 256] = e1;
  red[tid] = e0 + e1;
  __syncthreads();
  for (int s = 128; s > 0; s >>= 1) {
    if (tid < s) red[tid] += red[tid + s];
    __syncthreads();
  }
  float inv = 1.f / red[0];
  float a0 = 0.f, a1 = 0.f, a2 = 0.f, a3 = 0.f;
  const int d0 = lane * 4;
  for (int i = 0; i < 128; ++i) {
    int t = wave * 128 + i;
    float w = sS[t];
    unsigned long long hv = *(const unsigned long long*)&hout[hb_base + (size_t)t * 256 + d0];
    unsigned lo = (unsigned)hv, hi = (unsigned)(hv >> 32);
    a0 += w * bcl(lo); a1 += w * bch(lo); a2 += w * bcl(hi); a3 += w * bch(hi);
  }
  hb4[wave][d0] = a0; hb4[wave][d0 + 1] = a1; hb4[wave][d0 + 2] = a2; hb4[wave][d0 + 3] = a3;
  __syncthreads();
  h0S[tid] = (hb4[0][tid] + hb4[1][tid] + hb4[2][tid] + hb4[3][tid]) * inv;  // hbar
  __syncthreads();

  // ---- head: o0=hbar@Wv+bv ; o1=o0@Wo+bo ; z=relu(o1@W1+b1) ; out=z@W2+b2
  a = 0.f;
  for (int k = 0; k < 256; ++k) a += h0S[k] * Wv[(size_t)k * 256 + tid];
  oS[tid] = a + bv[tid];
  __syncthreads();
  a = 0.f;
  for (int k = 0; k < 256; ++k) a += oS[k] * Wo[(size_t)k * 256 + tid];
  o1S[tid] = a + bo[tid];
  __syncthreads();
  if (tid < 32) {
    a = 0.f;
    for (int k = 0; k < 256; ++k) a += o1S[k] * W1[k * 32 + tid];
    zS[tid] = fmaxf(a + b1[tid], 0.f);
  }
  __syncthreads();
  if (tid < 3) {
    a = 0.f;
    for (int j = 0; j < 32; ++j) a += zS[j] * W2[j * 3 + tid];
    out[b * 3 + tid] = a + b2[tid];
  }
}

// ---------------------------------------------------------------- launch
extern "C" void kernel_launch(void* const* d_in, const int* in_sizes, int n_in,
                              void* d_out, int out_size, void* d_ws, size_t ws_size,
                              hipStream_t stream) {
  const float* x  = (const float*)d_in[0];
  const float* Wi = (const float*)d_in[1];
  const float* Wh = (const float*)d_in[2];
  const float* bG = (const float*)d_in[3];
  const float* Wq = (const float*)d_in[4];
  const float* bq = (const float*)d_in[5];
  const float* Wk = (const float*)d_in[6];
  const float* bk = (const float*)d_in[7];
  const float* Wv = (const float*)d_in[8];
  const float* bv = (const float*)d_in[9];
  const float* Wo = (const float*)d_in[10];
  const float* bo = (const float*)d_in[11];
  const float* W1 = (const float*)d_in[12];
  const float* b1 = (const float*)d_in[13];
  const float* W2 = (const float*)d_in[14];
  const float* b2 = (const float*)d_in[15];
  float* out = (float*)d_out;
  char* ws = (char*)d_ws;

  unsigned short* xg   = (unsigned short*)(ws);              // 67,108,864 B
  unsigned short* hout = (unsigned short*)(ws + 67108864);   // 16,777,216 B
  unsigned short* xbf  = (unsigned short*)(ws + 83886080);   // 16,777,216 B
  unsigned short* WiT  = (unsigned short*)(ws + 100663296);  //    524,288 B
  unsigned short* WhP  = (unsigned short*)(ws + 101187584);  //    524,288 B
  // total ~101.7 MB of workspace

  prep_all<<<dim3(8704), dim3(256), 0, stream>>>(x, Wi, Wh, xbf, WiT, WhP);
  xg_gemm<<<dim3(8, 256), dim3(256), 0, stream>>>(xbf, WiT, bG, xg);
  lstm_scan<<<dim3(64), dim3(256), 0, stream>>>(WhP, xg, hout);
  attn_head<<<dim3(64), dim3(256), 0, stream>>>(hout, Wq, bq, Wk, bk, Wv, bv,
                                                Wo, bo, W1, b1, W2, b2, out);
}

// Round 5
// 1161.396 us; speedup vs baseline: 1.9759x; 1.2698x over previous
//
#include <hip/hip_runtime.h>
#include <hip/hip_bf16.h>

// ---------------------------------------------------------------------------
// myLSTM R5: exchange-free scan; per-wave Wh = 3 reg tiles + 2 LDS tiles +
// 3 L2-streamed tiles, 8 waves (2/SIMD) so the co-resident wave hides latency.
//
// Register-file wall (R2-R4 lesson): bf16 Wh = 512KB = 2048 regs = the ENTIRE
// CU register file. Any "all-resident" partition sits at 93-105% of the
// per-wave cap and the allocator spills scratch. R5 stops fighting it:
// steady-state ~196 regs/wave (cap 256 at 2 waves/SIMD), and the 3 non-
// resident tiles are streamed from L2 (Wh is shared read-only; per-XCD L2
// holds it; ~860cy/step of L2 traffic hidden under the 2483cy MFMA floor).
//
//   prep_all  : x->bf16 ; Wi -> WiT [1024][256] bf16 ; Wh -> WhP permuted
//               [1024][256] bf16, row' = w*128 + rt*16 + q*4 + r  <->
//               col_nat = gate(r)*256 + unit(w*32 + rt*4 + q).
//   xg_gemm   : xg = x@Wi + b (bf16 MFMA 128x128), PERMUTED [b][t][u][gate].
//   lstm_scan : 64 WGs (one batch each), 512 thr = 8 waves, 2/SIMD.
//               Wave w owns Wh rows' [w*128, w*128+128) = 8 tiles:
//               rt 0..2 registers, rt 3..4 LDS (XOR-swizzled), rt 5..7
//               streamed per step (issue points: t5 at step top, t6 after
//               pass 2, t7 after pass-5 MFMAs). h_{t-1} (512B) double-
//               buffered in LDS, broadcast B-fragment. 8 single-tile passes,
//               per-pass extraction (lane l16==rt owns unit w*32+l16*4+quad).
//               One barrier/step.
//   attn_head : fused attention + MLP head (block-local per batch).
// ---------------------------------------------------------------------------

typedef __attribute__((ext_vector_type(8))) short short8;   // 8 x bf16 (4 VGPR)
typedef __attribute__((ext_vector_type(4))) float float4v;  // MFMA acc

__device__ __forceinline__ unsigned short f2bf(float f) {  // RNE f32->bf16
  unsigned u = __builtin_bit_cast(unsigned, f);
  return (unsigned short)((u + 0x7fffu + ((u >> 16) & 1u)) >> 16);
}
__device__ __forceinline__ float bf2f(unsigned short h) {
  return __builtin_bit_cast(float, ((unsigned)h) << 16);
}
__device__ __forceinline__ float bcl(unsigned u) {  // low bf16 of dword
  return __builtin_bit_cast(float, u << 16);
}
__device__ __forceinline__ float bch(unsigned u) {  // high bf16 of dword
  return __builtin_bit_cast(float, u & 0xffff0000u);
}
// v_rcp_f32 (1 ulp) instead of precise div: error ~1e-7, invisible vs bf16.
__device__ __forceinline__ float sigm(float x) {
  return __builtin_amdgcn_rcpf(1.f + __expf(-x));
}
__device__ __forceinline__ float tanh_f(float x) {
  return 1.f - 2.f * __builtin_amdgcn_rcpf(1.f + __expf(2.f * x));
}

// ---------------------------------------------------------------- prep (fused)
// blocks [0,8192)    : x fp32 -> bf16                (8,388,608 elems)
// blocks [8192,8448) : Wi [256,1024] -> WiT [1024][256] bf16
// blocks [8448,8704) : Wh [256,1024] -> WhP [1024][256] bf16, row-permuted
__global__ void prep_all(const float* __restrict__ x,
                         const float* __restrict__ Wi,
                         const float* __restrict__ Wh,
                         unsigned short* __restrict__ xbf,
                         unsigned short* __restrict__ WiT,
                         unsigned short* __restrict__ WhP) {
  const int bid = blockIdx.x, tid = threadIdx.x;
  if (bid < 8192) {
    size_t i = ((size_t)bid * 256 + tid) * 4;
    float4 v = *(const float4*)&x[i];
    unsigned long long pk = (unsigned long long)f2bf(v.x)
                          | ((unsigned long long)f2bf(v.y) << 16)
                          | ((unsigned long long)f2bf(v.z) << 32)
                          | ((unsigned long long)f2bf(v.w) << 48);
    *(unsigned long long*)&xbf[i] = pk;
  } else if (bid < 8448) {
    size_t i = ((size_t)(bid - 8192) * 256 + tid) * 4;
    float4 v = *(const float4*)&Wi[i];
    int k = (int)(i >> 10), n = (int)(i & 1023);
    WiT[(size_t)(n + 0) * 256 + k] = f2bf(v.x);
    WiT[(size_t)(n + 1) * 256 + k] = f2bf(v.y);
    WiT[(size_t)(n + 2) * 256 + k] = f2bf(v.z);
    WiT[(size_t)(n + 3) * 256 + k] = f2bf(v.w);
  } else {
    size_t i0 = ((size_t)(bid - 8448) * 256 + tid) * 4;
    int row = (int)(i0 >> 8);  // row' (same for all 4 elems)
    // row' = w*128 + rt*16 + q*4 + r -> col_nat = r*256 + w*32 + rt*4 + q
    int colnat = (row & 3) * 256 + (row >> 7) * 32 + ((row >> 4) & 7) * 4 +
                 ((row >> 2) & 3);
    unsigned long long pk = 0;
#pragma unroll
    for (int j = 0; j < 4; ++j) {
      int k = (int)((i0 + j) & 255);
      pk |= (unsigned long long)f2bf(Wh[(size_t)k * 1024 + colnat]) << (16 * j);
    }
    *(unsigned long long*)&WhP[i0] = pk;
  }
}

// ---------------------------------------------------------------- xg = x@Wi+b
#define XKP 40  // LDS k-pitch (shorts): 80B rows -> 16B-aligned b128, ~2-way banks
__global__ __launch_bounds__(256) void xg_gemm(const unsigned short* __restrict__ xbf,
                                               const unsigned short* __restrict__ WiT,
                                               const float* __restrict__ bias,
                                               unsigned short* __restrict__ xg) {
  __shared__ unsigned short As[128 * XKP];
  __shared__ unsigned short Bs[128 * XKP];
  const int tid = threadIdx.x;
  const int n0 = blockIdx.x * 128, m0 = blockIdx.y * 128;
  const int wave = tid >> 6, lane = tid & 63, quad = lane >> 4, l16 = lane & 15;
  const int wm = wave >> 1, wn = wave & 1;

  float4v acc[4][4];
#pragma unroll
  for (int i = 0; i < 4; ++i)
#pragma unroll
    for (int j = 0; j < 4; ++j) acc[i][j] = (float4v){0.f, 0.f, 0.f, 0.f};

  const int rr = tid >> 2, c8 = (tid & 3) * 8;  // staging coords (16B per thread)
  for (int k0 = 0; k0 < 256; k0 += 32) {
#pragma unroll
    for (int pp = 0; pp < 2; ++pp) {
      int r = pp * 64 + rr;
      *(uint4*)&As[r * XKP + c8] = *(const uint4*)&xbf[(size_t)(m0 + r) * 256 + k0 + c8];
      *(uint4*)&Bs[r * XKP + c8] = *(const uint4*)&WiT[(size_t)(n0 + r) * 256 + k0 + c8];
    }
    __syncthreads();
#pragma unroll
    for (int mt = 0; mt < 4; ++mt) {
      short8 af = *(const short8*)&As[(wm * 64 + mt * 16 + l16) * XKP + quad * 8];
#pragma unroll
      for (int nt = 0; nt < 4; ++nt) {
        short8 bf = *(const short8*)&Bs[(wn * 64 + nt * 16 + l16) * XKP + quad * 8];
        acc[mt][nt] = __builtin_amdgcn_mfma_f32_16x16x32_bf16(af, bf, acc[mt][nt], 0, 0, 0);
      }
    }
    __syncthreads();
  }
  // epilogue: +bias, bf16 store, PERMUTED layout for the scan:
  //   xg[((b*512 + t)*256 + u)*4 + gate]   (4 gates of a unit contiguous, 8B)
#pragma unroll
  for (int nt = 0; nt < 4; ++nt) {
    int col = n0 + wn * 64 + nt * 16 + l16;
    int gate = col >> 8, u = col & 255;
    float bv = bias[col];
#pragma unroll
    for (int mt = 0; mt < 4; ++mt) {
#pragma unroll
      for (int r = 0; r < 4; ++r) {
        int row = m0 + wm * 64 + mt * 16 + quad * 4 + r;
        int b = row >> 9, t = row & 511;
        xg[(((size_t)b * 512 + t) * 256 + u) * 4 + gate] = f2bf(acc[mt][nt][r] + bv);
      }
    }
  }
}

// ---------------------------------------------------------------- LSTM scan
// 64 WGs, one batch each. 512 threads = 8 waves, 2 waves/SIMD (cap 256 regs).
// Wave w owns Wh rows' [w*128, w*128+128) = 8 tiles (rt 0..7):
//   rt 0..2 -> registers (96 VGPR); rt 3..4 -> LDS slot w*2+(rt-3), swizzled;
//   rt 5..7 -> streamed from L2 each step (loop-invariant addresses).
// Lane (quad, l16<8) owns unit u = w*32 + l16*4 + quad; act tile rt == l16.
__global__ __launch_bounds__(512, 2) void lstm_scan(
    const unsigned short* __restrict__ WhP,  // [1024][256] bf16 (permuted rows)
    const unsigned short* __restrict__ xg,   // [b][t][u][gate] bf16
    unsigned short* __restrict__ hout) {
  __shared__ unsigned short WhL[16 * 4096];     // 16 tiles x 8KB = 131072 B
  __shared__ unsigned short hA[2][256];         // 1 KB, double-buffered h
  const int tid = threadIdx.x;
  const int b = blockIdx.x;  // batch
  const int wave = tid >> 6, lane = tid & 63, quad = lane >> 4, l16 = lane & 15;

  // ---- 3 register tiles (rt = 0..2)
  short8 frA[3][8];
#pragma unroll
  for (int rt = 0; rt < 3; ++rt) {
    const unsigned short* src =
        WhP + ((size_t)wave * 128 + rt * 16 + l16) * 256 + quad * 8;
#pragma unroll
    for (int kt = 0; kt < 8; ++kt)
      frA[rt][kt] = *(const short8*)&src[kt * 32];
  }
  // ---- 2 LDS tiles (rt = 3,4) -> slots wave*2, wave*2+1, XOR-swizzled
#pragma unroll
  for (int i = 0; i < 16; ++i) {
    int rt = 3 + (i >> 3);
    int chunk = (i & 7) * 64 + lane;     // 0..511 16B-chunks within the tile
    int rw = chunk >> 5, ch = chunk & 31;
    uint4 v = *(const uint4*)&WhP[((size_t)wave * 128 + rt * 16 + rw) * 256 + ch * 8];
    *(uint4*)((char*)WhL + (wave * 2 + rt - 3) * 8192 + rw * 512 +
              ((ch * 16) ^ ((rw & 7) << 4))) = v;
  }
  ((unsigned short*)hA)[tid] = 0;        // h_{-1} = 0 (both buffers; 512 shorts)
  __syncthreads();

  const bool act = (l16 < 8);
  const int u = wave * 32 + l16 * 4 + quad;    // this lane's unit (if act)
  const unsigned short* xgp = xg + ((size_t)b * 512 * 256 + u) * 4;
  unsigned short* houtp = hout + (size_t)b * 512 * 256 + u;
  const char* ldsT = (const char*)WhL + wave * 2 * 8192 + l16 * 512;
  // stream tile bases (loop-invariant -> L2-resident)
  const unsigned short* sp5 = WhP + ((size_t)wave * 128 + 5 * 16 + l16) * 256 + quad * 8;
  const unsigned short* sp6 = WhP + ((size_t)wave * 128 + 6 * 16 + l16) * 256 + quad * 8;
  const unsigned short* sp7 = WhP + ((size_t)wave * 128 + 7 * 16 + l16) * 256 + quad * 8;
  float c = 0.f;

  for (int t = 0; t < 512; ++t) {
    // ---- issue stream tile 5 (consumed in pass 5, ~1500cy later)
    short8 sb[8];
#pragma unroll
    for (int kt = 0; kt < 8; ++kt) sb[kt] = *(const short8*)&sp5[kt * 32];

    // xg(t): 4 gates of this lane's unit, 8B
    unsigned long long xv = 0;
    if (act) xv = *(const unsigned long long*)(xgp + (size_t)t * 1024);

    // h_{t-1} broadcast fragments (conflict-free broadcast reads)
    const char* hbuf = (const char*)hA[t & 1];
    short8 hb8[8];
#pragma unroll
    for (int kt = 0; kt < 8; ++kt)
      hb8[kt] = *(const short8*)(hbuf + kt * 64 + quad * 16);

    float4v g4 = (float4v){0.f, 0.f, 0.f, 0.f};

    // ---- passes 0..2: register tiles
#pragma unroll
    for (int p = 0; p < 3; ++p) {
      float4v a = (float4v){0.f, 0.f, 0.f, 0.f};
#pragma unroll
      for (int kt = 0; kt < 8; ++kt)
        a = __builtin_amdgcn_mfma_f32_16x16x32_bf16(frA[p][kt], hb8[kt], a, 0, 0, 0);
      if (l16 == p) g4 = a;
    }

    // ---- issue stream tile 6 (consumed in pass 6)
    short8 sc[8];
#pragma unroll
    for (int kt = 0; kt < 8; ++kt) sc[kt] = *(const short8*)&sp6[kt * 32];

    // ---- passes 3,4: LDS tiles (swizzled)
#pragma unroll
    for (int p = 0; p < 2; ++p) {
      float4v a = (float4v){0.f, 0.f, 0.f, 0.f};
#pragma unroll
      for (int kt = 0; kt < 8; ++kt) {
        short8 al = *(const short8*)(ldsT + p * 8192 +
                                     ((kt * 64 + quad * 16) ^ ((l16 & 7) << 4)));
        a = __builtin_amdgcn_mfma_f32_16x16x32_bf16(al, hb8[kt], a, 0, 0, 0);
      }
      if (l16 == 3 + p) g4 = a;
    }

    // ---- pass 5: stream tile 5
    {
      float4v a = (float4v){0.f, 0.f, 0.f, 0.f};
#pragma unroll
      for (int kt = 0; kt < 8; ++kt)
        a = __builtin_amdgcn_mfma_f32_16x16x32_bf16(sb[kt], hb8[kt], a, 0, 0, 0);
      if (l16 == 5) g4 = a;
    }
    // ---- issue stream tile 7 (reuse sb; consumed in pass 7)
#pragma unroll
    for (int kt = 0; kt < 8; ++kt) sb[kt] = *(const short8*)&sp7[kt * 32];

    // ---- pass 6: stream tile 6
    {
      float4v a = (float4v){0.f, 0.f, 0.f, 0.f};
#pragma unroll
      for (int kt = 0; kt < 8; ++kt)
        a = __builtin_amdgcn_mfma_f32_16x16x32_bf16(sc[kt], hb8[kt], a, 0, 0, 0);
      if (l16 == 6) g4 = a;
    }
    // ---- pass 7: stream tile 7
    {
      float4v a = (float4v){0.f, 0.f, 0.f, 0.f};
#pragma unroll
      for (int kt = 0; kt < 8; ++kt)
        a = __builtin_amdgcn_mfma_f32_16x16x32_bf16(sb[kt], hb8[kt], a, 0, 0, 0);
      if (l16 == 7) g4 = a;
    }

    // ---- gates (active lanes own one unit each)
    if (act) {
      float gi = g4[0] + bf2f((unsigned short)(xv));
      float gf = g4[1] + bf2f((unsigned short)(xv >> 16));
      float gG = g4[2] + bf2f((unsigned short)(xv >> 32));
      float go = g4[3] + bf2f((unsigned short)(xv >> 48));
      float cc = sigm(gf) * c + sigm(gi) * tanh_f(gG);
      c = cc;
      unsigned short h16 = f2bf(sigm(go) * tanh_f(cc));
      hA[(t + 1) & 1][u] = h16;          // next buffer (disjoint from readers)
      houtp[(size_t)t * 256] = h16;      // h history for attention
    }
    __syncthreads();                     // ONE barrier per step
  }
}

// --------------------------------------------------- attention + head (fused)
__global__ __launch_bounds__(256) void attn_head(
    const unsigned short* __restrict__ hout,
    const float* __restrict__ Wq, const float* __restrict__ bq,
    const float* __restrict__ Wk, const float* __restrict__ bk,
    const float* __restrict__ Wv, const float* __restrict__ bv,
    const float* __restrict__ Wo, const float* __restrict__ bo,
    const float* __restrict__ W1, const float* __restrict__ b1,
    const float* __restrict__ W2, const float* __restrict__ b2,
    float* __restrict__ out) {
  __shared__ float h0S[256], q0S[256], red[256], usS[256], sS[512], hb4[4][256];
  __shared__ float oS[256], o1S[256], zS[32], cbS;
  const int b = blockIdx.x, tid = threadIdx.x, wave = tid >> 6, lane = tid & 63;
  const size_t hb_base = (size_t)b * 512 * 256;

  // ---- q0 = h0@Wq+bq ; u = Wk@(scale*q0) ; cb = scale*q0.bk
  h0S[tid] = bf2f(hout[hb_base + tid]);
  __syncthreads();
  float a = 0.f;
  for (int k = 0; k < 256; ++k) a += h0S[k] * Wq[(size_t)k * 256 + tid];
  q0S[tid] = a + bq[tid];
  __syncthreads();
  red[tid] = q0S[tid] * bk[tid];
  __syncthreads();
  for (int s = 128; s > 0; s >>= 1) {
    if (tid < s) red[tid] += red[tid + s];
    __syncthreads();
  }
  if (tid == 0) cbS = 0.0625f * red[0];
  float acq = 0.f;
  const float* wr = &Wk[(size_t)tid * 256];
  for (int e = 0; e < 256; e += 4) {
    float4 w = *(const float4*)&wr[e];
    acq += w.x * q0S[e] + w.y * q0S[e + 1] + w.z * q0S[e + 2] + w.w * q0S[e + 3];
  }
  usS[tid] = 0.0625f * acq;
  __syncthreads();

  // ---- scores = u.h[b,t]+cb -> softmax -> hbar = sum attn*h
  const float u0 = usS[lane * 4 + 0], u1 = usS[lane * 4 + 1];
  const float u2 = usS[lane * 4 + 2], u3 = usS[lane * 4 + 3];
  const float cbv = cbS;
  for (int i = 0; i < 128; ++i) {
    int t = i * 4 + wave;
    unsigned long long hv = *(const unsigned long long*)&hout[hb_base + (size_t)t * 256 + lane * 4];
    unsigned lo = (unsigned)hv, hi = (unsigned)(hv >> 32);
    float p = u0 * bcl(lo) + u1 * bch(lo) + u2 * bcl(hi) + u3 * bch(hi);
    for (int m = 1; m < 64; m <<= 1) p += __shfl_xor(p, m, 64);
    if (lane == 0) sS[t] = p + cbv;
  }
  __syncthreads();
  red[tid] = fmaxf(sS[tid], sS[tid + 256]);
  __syncthreads();
  for (int s = 128; s > 0; s >>= 1) {
    if (tid < s) red[tid] = fmaxf(red[tid], red[tid + s]);
    __syncthreads();
  }
  float mx = red[0];
  __syncthreads();
  float e0 = __expf(sS[tid] - mx), e1 = __expf(sS[tid + 256] - mx);
  sS[tid] = e0; sS[tid + 256] = e1;
  red[tid] = e0 + e1;
  __syncthreads();
  for (int s = 128; s > 0; s >>= 1) {
    if (tid < s) red[tid] += red[tid + s];
    __syncthreads();
  }
  float inv = 1.f / red[0];
  float a0 = 0.f, a1 = 0.f, a2 = 0.f, a3 = 0.f;
  const int d0 = lane * 4;
  for (int i = 0; i < 128; ++i) {
    int t = wave * 128 + i;
    float w = sS[t];
    unsigned long long hv = *(const unsigned long long*)&hout[hb_base + (size_t)t * 256 + d0];
    unsigned lo = (unsigned)hv, hi = (unsigned)(hv >> 32);
    a0 += w * bcl(lo); a1 += w * bch(lo); a2 += w * bcl(hi); a3 += w * bch(hi);
  }
  hb4[wave][d0] = a0; hb4[wave][d0 + 1] = a1; hb4[wave][d0 + 2] = a2; hb4[wave][d0 + 3] = a3;
  __syncthreads();
  h0S[tid] = (hb4[0][tid] + hb4[1][tid] + hb4[2][tid] + hb4[3][tid]) * inv;  // hbar
  __syncthreads();

  // ---- head: o0=hbar@Wv+bv ; o1=o0@Wo+bo ; z=relu(o1@W1+b1) ; out=z@W2+b2
  a = 0.f;
  for (int k = 0; k < 256; ++k) a += h0S[k] * Wv[(size_t)k * 256 + tid];
  oS[tid] = a + bv[tid];
  __syncthreads();
  a = 0.f;
  for (int k = 0; k < 256; ++k) a += oS[k] * Wo[(size_t)k * 256 + tid];
  o1S[tid] = a + bo[tid];
  __syncthreads();
  if (tid < 32) {
    a = 0.f;
    for (int k = 0; k < 256; ++k) a += o1S[k] * W1[k * 32 + tid];
    zS[tid] = fmaxf(a + b1[tid], 0.f);
  }
  __syncthreads();
  if (tid < 3) {
    a = 0.f;
    for (int j = 0; j < 32; ++j) a += zS[j] * W2[j * 3 + tid];
    out[b * 3 + tid] = a + b2[tid];
  }
}

// ---------------------------------------------------------------- launch
extern "C" void kernel_launch(void* const* d_in, const int* in_sizes, int n_in,
                              void* d_out, int out_size, void* d_ws, size_t ws_size,
                              hipStream_t stream) {
  const float* x  = (const float*)d_in[0];
  const float* Wi = (const float*)d_in[1];
  const float* Wh = (const float*)d_in[2];
  const float* bG = (const float*)d_in[3];
  const float* Wq = (const float*)d_in[4];
  const float* bq = (const float*)d_in[5];
  const float* Wk = (const float*)d_in[6];
  const float* bk = (const float*)d_in[7];
  const float* Wv = (const float*)d_in[8];
  const float* bv = (const float*)d_in[9];
  const float* Wo = (const float*)d_in[10];
  const float* bo = (const float*)d_in[11];
  const float* W1 = (const float*)d_in[12];
  const float* b1 = (const float*)d_in[13];
  const float* W2 = (const float*)d_in[14];
  const float* b2 = (const float*)d_in[15];
  float* out = (float*)d_out;
  char* ws = (char*)d_ws;

  unsigned short* xg   = (unsigned short*)(ws);              // 67,108,864 B
  unsigned short* hout = (unsigned short*)(ws + 67108864);   // 16,777,216 B
  unsigned short* xbf  = (unsigned short*)(ws + 83886080);   // 16,777,216 B
  unsigned short* WiT  = (unsigned short*)(ws + 100663296);  //    524,288 B
  unsigned short* WhP  = (unsigned short*)(ws + 101187584);  //    524,288 B
  // total ~101.7 MB of workspace

  prep_all<<<dim3(8704), dim3(256), 0, stream>>>(x, Wi, Wh, xbf, WiT, WhP);
  xg_gemm<<<dim3(8, 256), dim3(256), 0, stream>>>(xbf, WiT, bG, xg);
  lstm_scan<<<dim3(64), dim3(512), 0, stream>>>(WhP, xg, hout);
  attn_head<<<dim3(64), dim3(256), 0, stream>>>(hout, Wq, bq, Wk, bk, Wv, bv,
                                                Wo, bo, W1, b1, W2, b2, out);
}